// Round 4
// baseline (1492.591 us; speedup 1.0000x reference)
//
#include <hip/hip_runtime.h>

#define EPS_LN 1e-4f

// ===========================================================================
// Fast path: invert the scatter rulebook on-device into a per-output-row slot
// table (one gather-row index per kernel offset k, -1 if none), then compute
// each output row with PLAIN stores -- no global float atomics on the hot
// path (round-2/3 evidence: 134M device atomics = 67/cycle = the 835us wall,
// with VALU 18% and HBM 10% both idle). Rare duplicate (out,k) pairs
// (identical input coordinates, ~15k) go to an overflow list and are applied
// with atomics afterwards, with exact stats correction.
//
// ws layout (bytes):
//   [0,1024)                stats: [0..63] sum, [64..127] sumsq,
//                                  [128..191] scale, [192..255] shift
//   [1024, 1024+n_out*16)   slot table, int4 per output row (memset 0xFF)
//   [cnt_off, +4)           ovf_count
//   [cnt_off+16, ...)       ovf entries: int2 { g, s | (k<<28) }
// ===========================================================================

__global__ __launch_bounds__(256) void build_inverse_kernel(
    const int* __restrict__ gidx, const int* __restrict__ sidx,
    int* __restrict__ slot, int* __restrict__ ovf_count,
    int2* __restrict__ ovf, int ovf_cap, int P, int n_out) {
  const int k = blockIdx.y;
  const int p = blockIdx.x * blockDim.x + threadIdx.x;
  if (p >= P) return;
  const int i = k * P + p;
  const int s = sidx[i];
  if (s >= n_out) return;  // padding/dump row
  const int g = gidx[i];
  const int old = atomicExch(&slot[s * 4 + k], g);
  if (old != -1) {  // duplicate (s,k): divert the displaced rule
    const int pos = atomicAdd(ovf_count, 1);
    if (pos < ovf_cap) ovf[pos] = make_int2(old, s | (k << 28));
  }
}

// ---------------------------------------------------------------------------
// One wave per 2 output rows; lane == output channel. Slots software-
// pipelined; feats rows are wave-uniform broadcast float4 loads. W in LDS,
// XOR-swizzled so ds_read_b128 at 128B row stride is conflict-spread.
// Per-channel sum/sumsq fused (saves a full 500MB stats pass).
// ---------------------------------------------------------------------------
__global__ __launch_bounds__(256) void gather_conv_stats_kernel(
    const float* __restrict__ feats, const float* __restrict__ W,
    const int4* __restrict__ slot, float* __restrict__ out,
    float* __restrict__ ws, int n_out) {
  __shared__ float ls_w[4 * 64 * 32];  // [k][ch][c ^ ((ch&7)<<2)]
  __shared__ float ls_s[128];
  for (int i = threadIdx.x; i < 4 * 32 * 64; i += blockDim.x) {
    const int ch = i & 63;            // W layout: [k][c][ch]
    const int c = (i >> 6) & 31;
    const int k = i >> 11;
    ls_w[(((k << 6) + ch) << 5) + (c ^ ((ch & 7) << 2))] = W[i];
  }
  if (threadIdx.x < 128) ls_s[threadIdx.x] = 0.f;
  __syncthreads();

  const int lane = threadIdx.x & 63;
  const int swz = (lane & 7) << 2;
  const int wave = (blockIdx.x * blockDim.x + threadIdx.x) >> 6;
  const int waveStride = (gridDim.x * blockDim.x) >> 6;
  float s1 = 0.f, s2 = 0.f;

  const long rstep = (long)waveStride * 2;
  long r0 = (long)wave * 2;
  int4 cur0 = make_int4(-1, -1, -1, -1), cur1 = make_int4(-1, -1, -1, -1);
  if (r0 < n_out) cur0 = slot[r0];
  if (r0 + 1 < n_out) cur1 = slot[r0 + 1];

  for (; r0 < n_out; r0 += rstep) {
    const long rn = r0 + rstep;  // prefetch next iteration's slots
    int4 nx0 = make_int4(-1, -1, -1, -1), nx1 = make_int4(-1, -1, -1, -1);
    if (rn < n_out) nx0 = slot[rn];
    if (rn + 1 < n_out) nx1 = slot[rn + 1];

    const bool has1 = (r0 + 1 < n_out);
    const int c0 = (cur0.x >= 0) + (cur0.y >= 0) + (cur0.z >= 0) + (cur0.w >= 0);
    const int c1 = (cur1.x >= 0) + (cur1.y >= 0) + (cur1.z >= 0) + (cur1.w >= 0);

    float accA = 0.f, accB = 0.f;
    if (has1 && c0 == 1 && c1 == 1) {
      // ~85% of row pairs: exactly one contribution each -> branchless k
      // extraction, both rows' 8+8 loads issued together (latency overlap).
      const int gA = max(max(cur0.x, cur0.y), max(cur0.z, cur0.w));
      const int gB = max(max(cur1.x, cur1.y), max(cur1.z, cur1.w));
      const int kA = (cur0.x >= 0) ? 0 : (cur0.y >= 0) ? 1 : (cur0.z >= 0) ? 2 : 3;
      const int kB = (cur1.x >= 0) ? 0 : (cur1.y >= 0) ? 1 : (cur1.z >= 0) ? 2 : 3;
      const float4* __restrict__ fA = (const float4*)(feats + (long)gA * 32);
      const float4* __restrict__ fB = (const float4*)(feats + (long)gB * 32);
      float4 a[8], b[8];
#pragma unroll
      for (int j = 0; j < 8; ++j) a[j] = fA[j];
#pragma unroll
      for (int j = 0; j < 8; ++j) b[j] = fB[j];
      const float* wA = ls_w + (((kA << 6) + lane) << 5);
      const float* wB = ls_w + (((kB << 6) + lane) << 5);
      float aa0 = 0, aa1 = 0, aa2 = 0, aa3 = 0;
      float bb0 = 0, bb1 = 0, bb2 = 0, bb3 = 0;
#pragma unroll
      for (int j = 0; j < 8; ++j) {
        const float4 wa = *(const float4*)(wA + ((4 * j) ^ swz));
        const float4 wb = *(const float4*)(wB + ((4 * j) ^ swz));
        aa0 = fmaf(a[j].x, wa.x, aa0); aa1 = fmaf(a[j].y, wa.y, aa1);
        aa2 = fmaf(a[j].z, wa.z, aa2); aa3 = fmaf(a[j].w, wa.w, aa3);
        bb0 = fmaf(b[j].x, wb.x, bb0); bb1 = fmaf(b[j].y, wb.y, bb1);
        bb2 = fmaf(b[j].z, wb.z, bb2); bb3 = fmaf(b[j].w, wb.w, bb3);
      }
      accA = (aa0 + aa1) + (aa2 + aa3);
      accB = (bb0 + bb1) + (bb2 + bb3);
    } else {
      // general path (multi-contribution rows, tail)
      const int gs0[4] = {cur0.x, cur0.y, cur0.z, cur0.w};
#pragma unroll
      for (int k = 0; k < 4; ++k) {
        const int g = gs0[k];
        if (g < 0) continue;
        const float4* __restrict__ fp = (const float4*)(feats + (long)g * 32);
        const float* wl = ls_w + (((k << 6) + lane) << 5);
        float4 f[8];
#pragma unroll
        for (int j = 0; j < 8; ++j) f[j] = fp[j];
        float t0 = 0, t1 = 0, t2 = 0, t3 = 0;
#pragma unroll
        for (int j = 0; j < 8; ++j) {
          const float4 wv = *(const float4*)(wl + ((4 * j) ^ swz));
          t0 = fmaf(f[j].x, wv.x, t0); t1 = fmaf(f[j].y, wv.y, t1);
          t2 = fmaf(f[j].z, wv.z, t2); t3 = fmaf(f[j].w, wv.w, t3);
        }
        accA += (t0 + t1) + (t2 + t3);
      }
      if (has1) {
        const int gs1[4] = {cur1.x, cur1.y, cur1.z, cur1.w};
#pragma unroll
        for (int k = 0; k < 4; ++k) {
          const int g = gs1[k];
          if (g < 0) continue;
          const float4* __restrict__ fp = (const float4*)(feats + (long)g * 32);
          const float* wl = ls_w + (((k << 6) + lane) << 5);
          float4 f[8];
#pragma unroll
          for (int j = 0; j < 8; ++j) f[j] = fp[j];
          float t0 = 0, t1 = 0, t2 = 0, t3 = 0;
#pragma unroll
          for (int j = 0; j < 8; ++j) {
            const float4 wv = *(const float4*)(wl + ((4 * j) ^ swz));
            t0 = fmaf(f[j].x, wv.x, t0); t1 = fmaf(f[j].y, wv.y, t1);
            t2 = fmaf(f[j].z, wv.z, t2); t3 = fmaf(f[j].w, wv.w, t3);
          }
          accB += (t0 + t1) + (t2 + t3);
        }
      }
    }

    out[(r0 << 6) + lane] = accA;          // plain coalesced 256B store
    s1 += accA; s2 += accA * accA;
    if (has1) {
      out[((r0 + 1) << 6) + lane] = accB;
      s1 += accB; s2 += accB * accB;
    }
    cur0 = nx0; cur1 = nx1;
  }

  atomicAdd(&ls_s[lane], s1);
  atomicAdd(&ls_s[64 + lane], s2);
  __syncthreads();
  if (threadIdx.x < 128) atomicAdd(&ws[threadIdx.x], ls_s[threadIdx.x]);
}

// ---------------------------------------------------------------------------
// Apply displaced duplicate rules (~15k) with atomics; correct the fused
// stats exactly using atomicAdd's returned old value:
//   d(sum) = acc, d(sumsq) = new^2 - old^2 = acc*(2*old+acc).
// ---------------------------------------------------------------------------
__global__ __launch_bounds__(256) void overflow_kernel(
    const float* __restrict__ feats, const float* __restrict__ W,
    const int* __restrict__ ovf_count, const int2* __restrict__ ovf,
    float* __restrict__ out, float* __restrict__ ws, int ovf_cap) {
  const int cnt = min(*ovf_count, ovf_cap);
  const int lane = threadIdx.x & 63;
  const int wave = (blockIdx.x * blockDim.x + threadIdx.x) >> 6;
  const int waveStride = (gridDim.x * blockDim.x) >> 6;
  for (int e = wave; e < cnt; e += waveStride) {
    const int2 v = ovf[e];
    const int g = v.x;
    const int s = v.y & 0x0FFFFFFF;
    const int k = ((unsigned)v.y) >> 28;
    const float4* __restrict__ fp = (const float4*)(feats + (long)g * 32);
    float acc = 0.f;
#pragma unroll
    for (int j = 0; j < 8; ++j) {
      const float4 f = fp[j];
      acc = fmaf(f.x, W[(((k << 5) + 4 * j + 0) << 6) + lane], acc);
      acc = fmaf(f.y, W[(((k << 5) + 4 * j + 1) << 6) + lane], acc);
      acc = fmaf(f.z, W[(((k << 5) + 4 * j + 2) << 6) + lane], acc);
      acc = fmaf(f.w, W[(((k << 5) + 4 * j + 3) << 6) + lane], acc);
    }
    const float old = atomicAdd(out + ((long)s << 6) + lane, acc);
    atomicAdd(&ws[lane], acc);
    atomicAdd(&ws[64 + lane], acc * (2.f * old + acc));
  }
}

__global__ void finalize_stats_kernel(float* __restrict__ ws,
                                      const float* __restrict__ gamma,
                                      const float* __restrict__ beta,
                                      float inv_n) {
  const int c = threadIdx.x;  // 64 threads
  const float mean = ws[c] * inv_n;
  const float var = ws[64 + c] * inv_n - mean * mean;
  const float sc = rsqrtf(var + EPS_LN) * gamma[c];
  ws[128 + c] = sc;
  ws[192 + c] = beta[c] - mean * sc;
}

__global__ __launch_bounds__(256) void normalize_kernel(
    float4* __restrict__ out, const float* __restrict__ ws, long total4) {
  const long stride = (long)gridDim.x * blockDim.x;
  const int cb = (threadIdx.x << 2) & 63;
  const float4 sc = *(const float4*)(ws + 128 + cb);
  const float4 sh = *(const float4*)(ws + 192 + cb);
  for (long i = (long)blockIdx.x * blockDim.x + threadIdx.x; i < total4; i += stride) {
    float4 x = out[i];
    x.x = fmaxf(fmaf(x.x, sc.x, sh.x), 0.f);
    x.y = fmaxf(fmaf(x.y, sc.y, sh.y), 0.f);
    x.z = fmaxf(fmaf(x.z, sc.z, sh.z), 0.f);
    x.w = fmaxf(fmaf(x.w, sc.w, sh.w), 0.f);
    out[i] = x;
  }
}

// ---------------- fallback (round-2 path, if ws too small) ----------------
__global__ __launch_bounds__(256) void scatter_conv_kernel(
    const float* __restrict__ feats, const float* __restrict__ W,
    const int* __restrict__ gidx, const int* __restrict__ sidx,
    float* __restrict__ out, int P, int n_out) {
  const int lane = threadIdx.x & 63;
  const int k = blockIdx.y;
  const int wavesPerBlock = blockDim.x >> 6;
  const int wave = blockIdx.x * wavesPerBlock + (threadIdx.x >> 6);
  const int waveStride = gridDim.x * wavesPerBlock;
  float w[32];
#pragma unroll
  for (int c = 0; c < 32; ++c) w[c] = W[((k * 32 + c) << 6) + lane];
  const int base = k * P;
  for (int p = wave; p < P; p += waveStride) {
    const int g = gidx[base + p];
    const int s = sidx[base + p];
    const float4* __restrict__ fp = (const float4*)(feats + (long)g * 32);
    float4 f[8];
#pragma unroll
    for (int j = 0; j < 8; ++j) f[j] = fp[j];
    float a0 = 0, a1 = 0, a2 = 0, a3 = 0;
#pragma unroll
    for (int j = 0; j < 8; ++j) {
      a0 = fmaf(f[j].x, w[4 * j + 0], a0);
      a1 = fmaf(f[j].y, w[4 * j + 1], a1);
      a2 = fmaf(f[j].z, w[4 * j + 2], a2);
      a3 = fmaf(f[j].w, w[4 * j + 3], a3);
    }
    if (s < n_out) atomicAdd(out + ((long)s << 6) + lane, (a0 + a1) + (a2 + a3));
  }
}

__global__ __launch_bounds__(256) void stats_kernel(
    const float4* __restrict__ out, float* __restrict__ ws, long total4) {
  const long stride = (long)gridDim.x * blockDim.x;
  float s1[4] = {0.f, 0.f, 0.f, 0.f};
  float s2[4] = {0.f, 0.f, 0.f, 0.f};
  for (long i = (long)blockIdx.x * blockDim.x + threadIdx.x; i < total4; i += stride) {
    float4 x = out[i];
    s1[0] += x.x; s2[0] += x.x * x.x;
    s1[1] += x.y; s2[1] += x.y * x.y;
    s1[2] += x.z; s2[2] += x.z * x.z;
    s1[3] += x.w; s2[3] += x.w * x.w;
  }
  __shared__ float ls[128];
  if (threadIdx.x < 128) ls[threadIdx.x] = 0.f;
  __syncthreads();
  const int cb = (threadIdx.x << 2) & 63;
#pragma unroll
  for (int j = 0; j < 4; ++j) {
    atomicAdd(&ls[cb + j], s1[j]);
    atomicAdd(&ls[64 + cb + j], s2[j]);
  }
  __syncthreads();
  if (threadIdx.x < 128) atomicAdd(&ws[threadIdx.x], ls[threadIdx.x]);
}

extern "C" void kernel_launch(void* const* d_in, const int* in_sizes, int n_in,
                              void* d_out, int out_size, void* d_ws, size_t ws_size,
                              hipStream_t stream) {
  const float* feats = (const float*)d_in[0];
  const float* W     = (const float*)d_in[1];
  const float* gamma = (const float*)d_in[2];
  const float* beta  = (const float*)d_in[3];
  const int*   gidx  = (const int*)d_in[4];
  const int*   sidx  = (const int*)d_in[5];

  const int P = in_sizes[4] / 4;    // KVOL == 4
  const int n_out = out_size / 64;  // COUT == 64
  float* out = (float*)d_out;
  float* ws  = (float*)d_ws;
  const long total4 = (long)out_size / 4;

  char* wsb = (char*)d_ws;
  const size_t slots_off = 1024;
  const size_t slots_bytes = (size_t)n_out * 16;
  const size_t cnt_off = slots_off + slots_bytes;
  const size_t ovf_off = cnt_off + 16;
  const size_t need = ovf_off + (size_t)65536 * 8;

  if (ws_size >= need) {
    int*  slot = (int*)(wsb + slots_off);
    int*  cnt  = (int*)(wsb + cnt_off);
    int2* ovf  = (int2*)(wsb + ovf_off);
    const size_t cap_sz = (ws_size - ovf_off) / 8;
    const int ovf_cap = cap_sz > (size_t)(1 << 26) ? (1 << 26) : (int)cap_sz;

    hipMemsetAsync(wsb, 0, 1024, stream);            // stats block
    hipMemsetAsync(slot, 0xFF, slots_bytes, stream); // slots = -1
    hipMemsetAsync(cnt, 0, 16, stream);              // ovf count

    dim3 bgrid((P + 255) / 256, 4);
    build_inverse_kernel<<<bgrid, 256, 0, stream>>>(gidx, sidx, slot, cnt, ovf,
                                                    ovf_cap, P, n_out);
    gather_conv_stats_kernel<<<2048, 256, 0, stream>>>(feats, W, (const int4*)slot,
                                                       out, ws, n_out);
    overflow_kernel<<<256, 256, 0, stream>>>(feats, W, cnt, ovf, out, ws, ovf_cap);
    finalize_stats_kernel<<<1, 64, 0, stream>>>(ws, gamma, beta, 1.0f / (float)n_out);
    normalize_kernel<<<2048, 256, 0, stream>>>((float4*)out, ws, total4);
  } else {
    hipMemsetAsync(d_out, 0, (size_t)out_size * sizeof(float), stream);
    hipMemsetAsync(d_ws, 0, 256 * sizeof(float), stream);
    dim3 sgrid(2048, 4);
    scatter_conv_kernel<<<sgrid, 256, 0, stream>>>(feats, W, gidx, sidx, out, P, n_out);
    stats_kernel<<<2048, 256, 0, stream>>>((const float4*)out, ws, total4);
    finalize_stats_kernel<<<1, 64, 0, stream>>>(ws, gamma, beta, 1.0f / (float)n_out);
    normalize_kernel<<<2048, 256, 0, stream>>>((float4*)out, ws, total4);
  }
}

// Round 5
// 1241.608 us; speedup vs baseline: 1.2021x; 1.2021x over previous
//
#include <hip/hip_runtime.h>

#define EPS_LN 1e-4f

// ===========================================================================
// Round-5 structure (evidence-driven):
//  - r3: 134M global float atomics = the wall (835us, all pipes idle).
//  - r4: inverted-table gather put W in LDS -> 8KB LDS read per output row
//        (64 lanes x 128B) + 8-way conflicts = new wall (778us, 6.5e7 confl).
//  Fix: keep the ORIGINAL per-k rule stream (k uniform per block -> W in 32
//  VGPRs, zero LDS), and kill atomics via a contribution-count table:
//  ~97% of rows have exactly 1 contributing rule -> plain store + fused
//  stats; the ~3% multi rows are pre-zeroed and accumulated atomically
//  (~120K rules = 4% of r3's atomic volume), their stats done in a tiny
//  follow-up pass.
//
// ws layout: [0,1KB) stats (sum/sumsq/scale/shift), [1KB, ...) count table
//            of (n_out+1) ints.
// ===========================================================================

// Pass 1: count contributions per output row (padding rows hit count[n_out]).
__global__ __launch_bounds__(256) void count_kernel(
    const int* __restrict__ sidx, int* __restrict__ count, int P) {
  const int k = blockIdx.y;
  const int p = blockIdx.x * blockDim.x + threadIdx.x;
  if (p < P) atomicAdd(&count[sidx[k * P + p]], 1);
}

// Pass 1b: zero the rows that will be accumulated atomically (count >= 2).
__global__ __launch_bounds__(256) void zero_multi_kernel(
    const int* __restrict__ count, float* __restrict__ out, int n_out) {
  const int lane = threadIdx.x & 63;
  const int wave = (blockIdx.x * blockDim.x + threadIdx.x) >> 6;
  const int wstep = (gridDim.x * blockDim.x) >> 6;
  for (int r = wave; r < n_out; r += wstep)
    if (count[r] >= 2) out[((long)r << 6) + lane] = 0.f;
}

// Pass 2: the conv. One wave per rule; lane == output channel; k uniform per
// block (blockIdx.y) so W[k][:,lane] sits in 32 VGPRs. Rules stream linearly;
// feats rows (wave-uniform broadcast float4 loads) are software-pipelined
// 2-deep via the A/B unrolled rotation (no register copies).
__global__ __launch_bounds__(256, 4) void conv_kernel(
    const float* __restrict__ feats, const float* __restrict__ W,
    const int* __restrict__ gidx, const int* __restrict__ sidx,
    const int* __restrict__ count, float* __restrict__ out,
    float* __restrict__ ws, int P, int n_out) {
  const int lane = threadIdx.x & 63;
  const int k = blockIdx.y;
  const int wavesPerBlock = blockDim.x >> 6;
  const int wave = blockIdx.x * wavesPerBlock + (threadIdx.x >> 6);
  const int stride = gridDim.x * wavesPerBlock;

  __shared__ float ls[128];
  if (threadIdx.x < 128) ls[threadIdx.x] = 0.f;
  __syncthreads();

  float w[32];
#pragma unroll
  for (int c = 0; c < 32; ++c) w[c] = W[((k * 32 + c) << 6) + lane];

  const int base = k * P;
  float s1 = 0.f, s2 = 0.f;

  int sA = 0, cA = 0, sB = 0, cB = 0;
  float4 fA[8], fB[8];

  if (wave < P) {
    const int i = base + wave;
    const int g = gidx[i];
    sA = sidx[i]; cA = count[sA];
    const float4* fp = (const float4*)(feats + (long)g * 32);
#pragma unroll
    for (int j = 0; j < 8; ++j) fA[j] = fp[j];
  }
  if (wave + stride < P) {
    const int i = base + wave + stride;
    const int g = gidx[i];
    sB = sidx[i]; cB = count[sB];
    const float4* fp = (const float4*)(feats + (long)g * 32);
#pragma unroll
    for (int j = 0; j < 8; ++j) fB[j] = fp[j];
  }

  for (int p = wave; p < P; p += 2 * stride) {
    // ---- compute rule A (p); then refill A with rule p+2*stride ----
    {
      float a0 = 0, a1 = 0, a2 = 0, a3 = 0;
#pragma unroll
      for (int j = 0; j < 8; ++j) {
        a0 = fmaf(fA[j].x, w[4 * j + 0], a0);
        a1 = fmaf(fA[j].y, w[4 * j + 1], a1);
        a2 = fmaf(fA[j].z, w[4 * j + 2], a2);
        a3 = fmaf(fA[j].w, w[4 * j + 3], a3);
      }
      const float acc = (a0 + a1) + (a2 + a3);
      if (sA < n_out) {
        if (cA == 1) {
          out[((long)sA << 6) + lane] = acc;  // plain coalesced 256B store
          s1 += acc; s2 += acc * acc;         // fused stats (exactly once)
        } else {
          atomicAdd(out + ((long)sA << 6) + lane, acc);  // rare (~3%)
        }
      }
    }
    {
      const int pn = p + 2 * stride;
      if (pn < P) {
        const int i = base + pn;
        const int g = gidx[i];
        sA = sidx[i]; cA = count[sA];
        const float4* fp = (const float4*)(feats + (long)g * 32);
#pragma unroll
        for (int j = 0; j < 8; ++j) fA[j] = fp[j];
      }
    }
    // ---- compute rule B (p+stride); then refill B with p+3*stride ----
    if (p + stride < P) {
      float b0 = 0, b1 = 0, b2 = 0, b3 = 0;
#pragma unroll
      for (int j = 0; j < 8; ++j) {
        b0 = fmaf(fB[j].x, w[4 * j + 0], b0);
        b1 = fmaf(fB[j].y, w[4 * j + 1], b1);
        b2 = fmaf(fB[j].z, w[4 * j + 2], b2);
        b3 = fmaf(fB[j].w, w[4 * j + 3], b3);
      }
      const float acc = (b0 + b1) + (b2 + b3);
      if (sB < n_out) {
        if (cB == 1) {
          out[((long)sB << 6) + lane] = acc;
          s1 += acc; s2 += acc * acc;
        } else {
          atomicAdd(out + ((long)sB << 6) + lane, acc);
        }
      }
      const int pn = p + 3 * stride;
      if (pn < P) {
        const int i = base + pn;
        const int g = gidx[i];
        sB = sidx[i]; cB = count[sB];
        const float4* fp = (const float4*)(feats + (long)g * 32);
#pragma unroll
        for (int j = 0; j < 8; ++j) fB[j] = fp[j];
      }
    }
  }

  atomicAdd(&ls[lane], s1);
  atomicAdd(&ls[64 + lane], s2);
  __syncthreads();
  if (threadIdx.x < 128) atomicAdd(&ws[threadIdx.x], ls[threadIdx.x]);
}

// Pass 3: stats for the multi-contribution rows (must run after conv).
__global__ __launch_bounds__(256) void multi_stats_kernel(
    const int* __restrict__ count, const float* __restrict__ out,
    float* __restrict__ ws, int n_out) {
  const int lane = threadIdx.x & 63;
  const int wave = (blockIdx.x * blockDim.x + threadIdx.x) >> 6;
  const int wstep = (gridDim.x * blockDim.x) >> 6;
  float s1 = 0.f, s2 = 0.f;
  for (int r = wave; r < n_out; r += wstep) {
    if (count[r] >= 2) {
      const float v = out[((long)r << 6) + lane];
      s1 += v; s2 += v * v;
    }
  }
  __shared__ float ls[128];
  if (threadIdx.x < 128) ls[threadIdx.x] = 0.f;
  __syncthreads();
  atomicAdd(&ls[lane], s1);
  atomicAdd(&ls[64 + lane], s2);
  __syncthreads();
  if (threadIdx.x < 128) atomicAdd(&ws[threadIdx.x], ls[threadIdx.x]);
}

__global__ void finalize_stats_kernel(float* __restrict__ ws,
                                      const float* __restrict__ gamma,
                                      const float* __restrict__ beta,
                                      float inv_n) {
  const int c = threadIdx.x;  // 64 threads
  const float mean = ws[c] * inv_n;
  const float var = ws[64 + c] * inv_n - mean * mean;
  const float sc = rsqrtf(var + EPS_LN) * gamma[c];
  ws[128 + c] = sc;
  ws[192 + c] = beta[c] - mean * sc;
}

__global__ __launch_bounds__(256) void normalize_kernel(
    float4* __restrict__ out, const float* __restrict__ ws, long total4) {
  const long stride = (long)gridDim.x * blockDim.x;
  const int cb = (threadIdx.x << 2) & 63;
  const float4 sc = *(const float4*)(ws + 128 + cb);
  const float4 sh = *(const float4*)(ws + 192 + cb);
  for (long i = (long)blockIdx.x * blockDim.x + threadIdx.x; i < total4; i += stride) {
    float4 x = out[i];
    x.x = fmaxf(fmaf(x.x, sc.x, sh.x), 0.f);
    x.y = fmaxf(fmaf(x.y, sc.y, sh.y), 0.f);
    x.z = fmaxf(fmaf(x.z, sc.z, sh.z), 0.f);
    x.w = fmaxf(fmaf(x.w, sc.w, sh.w), 0.f);
    out[i] = x;
  }
}

// ---------------- fallback (round-2 path, if ws too small) ----------------
__global__ __launch_bounds__(256) void scatter_conv_kernel(
    const float* __restrict__ feats, const float* __restrict__ W,
    const int* __restrict__ gidx, const int* __restrict__ sidx,
    float* __restrict__ out, int P, int n_out) {
  const int lane = threadIdx.x & 63;
  const int k = blockIdx.y;
  const int wave = blockIdx.x * (blockDim.x >> 6) + (threadIdx.x >> 6);
  const int stride = gridDim.x * (blockDim.x >> 6);
  float w[32];
#pragma unroll
  for (int c = 0; c < 32; ++c) w[c] = W[((k * 32 + c) << 6) + lane];
  const int base = k * P;
  for (int p = wave; p < P; p += stride) {
    const int g = gidx[base + p];
    const int s = sidx[base + p];
    const float4* fp = (const float4*)(feats + (long)g * 32);
    float4 f[8];
#pragma unroll
    for (int j = 0; j < 8; ++j) f[j] = fp[j];
    float a0 = 0, a1 = 0, a2 = 0, a3 = 0;
#pragma unroll
    for (int j = 0; j < 8; ++j) {
      a0 = fmaf(f[j].x, w[4 * j + 0], a0);
      a1 = fmaf(f[j].y, w[4 * j + 1], a1);
      a2 = fmaf(f[j].z, w[4 * j + 2], a2);
      a3 = fmaf(f[j].w, w[4 * j + 3], a3);
    }
    if (s < n_out) atomicAdd(out + ((long)s << 6) + lane, (a0 + a1) + (a2 + a3));
  }
}

__global__ __launch_bounds__(256) void stats_kernel(
    const float4* __restrict__ out, float* __restrict__ ws, long total4) {
  const long stride = (long)gridDim.x * blockDim.x;
  float s1[4] = {0.f, 0.f, 0.f, 0.f};
  float s2[4] = {0.f, 0.f, 0.f, 0.f};
  for (long i = (long)blockIdx.x * blockDim.x + threadIdx.x; i < total4; i += stride) {
    float4 x = out[i];
    s1[0] += x.x; s2[0] += x.x * x.x;
    s1[1] += x.y; s2[1] += x.y * x.y;
    s1[2] += x.z; s2[2] += x.z * x.z;
    s1[3] += x.w; s2[3] += x.w * x.w;
  }
  __shared__ float ls[128];
  if (threadIdx.x < 128) ls[threadIdx.x] = 0.f;
  __syncthreads();
  const int cb = (threadIdx.x << 2) & 63;
#pragma unroll
  for (int j = 0; j < 4; ++j) {
    atomicAdd(&ls[cb + j], s1[j]);
    atomicAdd(&ls[64 + cb + j], s2[j]);
  }
  __syncthreads();
  if (threadIdx.x < 128) atomicAdd(&ws[threadIdx.x], ls[threadIdx.x]);
}

extern "C" void kernel_launch(void* const* d_in, const int* in_sizes, int n_in,
                              void* d_out, int out_size, void* d_ws, size_t ws_size,
                              hipStream_t stream) {
  const float* feats = (const float*)d_in[0];
  const float* W     = (const float*)d_in[1];
  const float* gamma = (const float*)d_in[2];
  const float* beta  = (const float*)d_in[3];
  const int*   gidx  = (const int*)d_in[4];
  const int*   sidx  = (const int*)d_in[5];

  const int P = in_sizes[4] / 4;    // KVOL == 4
  const int n_out = out_size / 64;  // COUT == 64
  float* out = (float*)d_out;
  float* ws  = (float*)d_ws;
  const long total4 = (long)out_size / 4;

  char* wsb = (char*)d_ws;
  const size_t count_off = 1024;
  const size_t count_bytes = ((size_t)n_out + 1) * sizeof(int);
  const size_t need = count_off + count_bytes;

  if (ws_size >= need) {
    int* count = (int*)(wsb + count_off);
    hipMemsetAsync(wsb, 0, 1024, stream);         // stats block
    hipMemsetAsync(count, 0, count_bytes, stream);

    dim3 cgrid((P + 255) / 256, 4);
    count_kernel<<<cgrid, 256, 0, stream>>>(sidx, count, P);
    zero_multi_kernel<<<4096, 256, 0, stream>>>(count, out, n_out);
    dim3 vgrid(512, 4);
    conv_kernel<<<vgrid, 256, 0, stream>>>(feats, W, gidx, sidx, count, out, ws,
                                           P, n_out);
    multi_stats_kernel<<<4096, 256, 0, stream>>>(count, out, ws, n_out);
    finalize_stats_kernel<<<1, 64, 0, stream>>>(ws, gamma, beta, 1.0f / (float)n_out);
    normalize_kernel<<<2048, 256, 0, stream>>>((float4*)out, ws, total4);
  } else {
    hipMemsetAsync(d_out, 0, (size_t)out_size * sizeof(float), stream);
    hipMemsetAsync(d_ws, 0, 256 * sizeof(float), stream);
    dim3 sgrid(2048, 4);
    scatter_conv_kernel<<<sgrid, 256, 0, stream>>>(feats, W, gidx, sidx, out, P, n_out);
    stats_kernel<<<2048, 256, 0, stream>>>((const float4*)out, ws, total4);
    finalize_stats_kernel<<<1, 64, 0, stream>>>(ws, gamma, beta, 1.0f / (float)n_out);
    normalize_kernel<<<2048, 256, 0, stream>>>((float4*)out, ws, total4);
  }
}

// Round 6
// 1059.316 us; speedup vs baseline: 1.4090x; 1.1721x over previous
//
#include <hip/hip_runtime.h>

#define EPS_LN 1e-4f
#define RPG 64    // rules per group (= 64 lanes, lane = rule for index loads)
#define TILES 8   // 8-rule gather tiles per group

// readlane a float component from a uniform source lane (no DS pipe)
#define RL(v, sl) __int_as_float(__builtin_amdgcn_readlane(__float_as_int(v), (sl)))

// ===========================================================================
// Evidence so far (r2/r4/r5 all ~780-835us with different structures):
//  - wall = memory-level parallelism: ~1MB in flight device-wide -> ~1TB/s.
//  - DS pipe (shfl) and LDS-broadcast W are per-CU serial walls; avoid both.
// Round-6 conv: per-lane batched gather (1 instr = 8 random 128B rows in
// flight, 4 VGPR), 8 tiles deep per group (64 lines/wave in flight);
// distribute row->all-lanes via v_readlane (VALU only); lane = out channel;
// W[k] in 32 VGPRs (k = blockIdx.y). Plain stores + fused stats for
// single-contribution rows (~97%), atomics for the compacted ~3%.
// ws: [0,1KB) stats | [1KB) nmulti | [2KB) count[n_out+1] | list[n_out]
// ===========================================================================

__global__ __launch_bounds__(256) void count_kernel(
    const int* __restrict__ sidx, int* __restrict__ count, int P) {
  const int k = blockIdx.y;
  const int p = blockIdx.x * blockDim.x + threadIdx.x;
  if (p < P) atomicAdd(&count[sidx[k * P + p]], 1);
}

__global__ __launch_bounds__(256) void compact_kernel(
    const int* __restrict__ count, int* __restrict__ list,
    int* __restrict__ nmulti, int n_out) {
  const int r = blockIdx.x * blockDim.x + threadIdx.x;
  if (r < n_out && count[r] >= 2) list[atomicAdd(nmulti, 1)] = r;
}

__global__ __launch_bounds__(256) void zero_list_kernel(
    const int* __restrict__ list, const int* __restrict__ nmulti,
    float* __restrict__ out) {
  const int n = *nmulti;
  const int lane = threadIdx.x & 63;
  const int wave = (blockIdx.x * blockDim.x + threadIdx.x) >> 6;
  const int wstep = (gridDim.x * blockDim.x) >> 6;
  for (int e = wave; e < n; e += wstep)
    out[((size_t)list[e] << 6) + lane] = 0.f;
}

__global__ __launch_bounds__(256) void conv_kernel(
    const float* __restrict__ feats, const float* __restrict__ W,
    const int* __restrict__ gidx, const int* __restrict__ sidx,
    const int* __restrict__ count, float* __restrict__ out,
    float* __restrict__ ws, int P, int n_out, int rpw) {
  const int lane = threadIdx.x & 63;
  const int k = blockIdx.y;
  const int wv = blockIdx.x * (blockDim.x >> 6) + (threadIdx.x >> 6);

  __shared__ float ls[128];
  if (threadIdx.x < 128) ls[threadIdx.x] = 0.f;
  __syncthreads();

  float w[32];  // W[k][:, lane] -- my output channel's column
#pragma unroll
  for (int c = 0; c < 32; ++c) w[c] = W[((k * 32 + c) << 6) + lane];

  const long base = (long)k * P;
  const int start = wv * rpw;
  const int end = min(start + rpw, P);
  float s1 = 0.f, s2 = 0.f;

  if (start < end) {
    // group-0 indexes (lane = rule): coalesced 256B loads
    int pg = start + lane;
    bool v = pg < end;
    int g = v ? gidx[base + pg] : 0;
    int s = v ? sidx[base + pg] : n_out;
    int c = count[s];

    for (int gs = start; gs < end; gs += RPG) {
      // -------- issue all 8 gathers: lane l <- rule l>>3, chunk l&7 -------
      float4 ring[TILES];
#pragma unroll
      for (int t = 0; t < TILES; ++t) {
        const int gq = __shfl(g, (t << 3) + (lane >> 3));  // 8 shfl/group
        ring[t] = ((const float4*)feats)[(size_t)gq * 8 + (lane & 7)];
      }
      // -------- prefetch next group's indexes under this group's compute --
      const int pn = gs + RPG + lane;
      const bool vn = pn < end;
      const int gN = vn ? gidx[base + pn] : 0;
      const int sN = vn ? sidx[base + pn] : n_out;
      const int cN = count[sN];

      // -------- compute: 8 tiles x 8 rules; lane = channel ----------------
#pragma unroll
      for (int t = 0; t < TILES; ++t) {
#pragma unroll 2
        for (int q = 0; q < 8; ++q) {
          float a0 = 0.f, a1 = 0.f, a2 = 0.f, a3 = 0.f;
#pragma unroll
          for (int j = 0; j < 8; ++j) {
            const int sl = (q << 3) + j;  // source lane holding chunk j
            a0 = fmaf(RL(ring[t].x, sl), w[4 * j + 0], a0);
            a1 = fmaf(RL(ring[t].y, sl), w[4 * j + 1], a1);
            a2 = fmaf(RL(ring[t].z, sl), w[4 * j + 2], a2);
            a3 = fmaf(RL(ring[t].w, sl), w[4 * j + 3], a3);
          }
          const float acc = (a0 + a1) + (a2 + a3);
          const int rl = (t << 3) + q;
          const int sq = __builtin_amdgcn_readlane(s, rl);  // uniform
          const int cq = __builtin_amdgcn_readlane(c, rl);  // uniform
          if (sq < n_out) {          // scalar branch (padding excluded)
            if (cq == 1) {
              out[((size_t)sq << 6) + lane] = acc;  // coalesced 256B store
              s1 += acc;
              s2 = fmaf(acc, acc, s2);
            } else {
              atomicAdd(out + ((size_t)sq << 6) + lane, acc);  // ~3%
            }
          }
        }
      }
      g = gN; s = sN; c = cN;
    }
  }

  atomicAdd(&ls[lane], s1);
  atomicAdd(&ls[64 + lane], s2);
  __syncthreads();
  if (threadIdx.x < 128) atomicAdd(&ws[threadIdx.x], ls[threadIdx.x]);
}

// stats of the multi-contribution rows, from the compacted list (post-conv)
__global__ __launch_bounds__(256) void multi_stats_kernel(
    const int* __restrict__ list, const int* __restrict__ nmulti,
    const float* __restrict__ out, float* __restrict__ ws) {
  const int n = *nmulti;
  const int lane = threadIdx.x & 63;
  const int wave = (blockIdx.x * blockDim.x + threadIdx.x) >> 6;
  const int wstep = (gridDim.x * blockDim.x) >> 6;
  float s1 = 0.f, s2 = 0.f;
  for (int e = wave; e < n; e += wstep) {
    const float v = out[((size_t)list[e] << 6) + lane];
    s1 += v; s2 = fmaf(v, v, s2);
  }
  __shared__ float ls[128];
  if (threadIdx.x < 128) ls[threadIdx.x] = 0.f;
  __syncthreads();
  atomicAdd(&ls[lane], s1);
  atomicAdd(&ls[64 + lane], s2);
  __syncthreads();
  if (threadIdx.x < 128) atomicAdd(&ws[threadIdx.x], ls[threadIdx.x]);
}

__global__ void finalize_stats_kernel(float* __restrict__ ws,
                                      const float* __restrict__ gamma,
                                      const float* __restrict__ beta,
                                      float inv_n) {
  const int c = threadIdx.x;  // 64 threads
  const float mean = ws[c] * inv_n;
  const float var = ws[64 + c] * inv_n - mean * mean;
  const float sc = rsqrtf(var + EPS_LN) * gamma[c];
  ws[128 + c] = sc;
  ws[192 + c] = beta[c] - mean * sc;
}

__global__ __launch_bounds__(256) void normalize_kernel(
    float4* __restrict__ out, const float* __restrict__ ws, long total4) {
  const long stride = (long)gridDim.x * blockDim.x;
  const int cb = (threadIdx.x << 2) & 63;
  const float4 sc = *(const float4*)(ws + 128 + cb);
  const float4 sh = *(const float4*)(ws + 192 + cb);
  for (long i = (long)blockIdx.x * blockDim.x + threadIdx.x; i < total4; i += stride) {
    float4 x = out[i];
    x.x = fmaxf(fmaf(x.x, sc.x, sh.x), 0.f);
    x.y = fmaxf(fmaf(x.y, sc.y, sh.y), 0.f);
    x.z = fmaxf(fmaf(x.z, sc.z, sh.z), 0.f);
    x.w = fmaxf(fmaf(x.w, sc.w, sh.w), 0.f);
    out[i] = x;
  }
}

// ---------------- fallback (if ws too small): r2 path ----------------
__global__ __launch_bounds__(256) void scatter_conv_kernel(
    const float* __restrict__ feats, const float* __restrict__ W,
    const int* __restrict__ gidx, const int* __restrict__ sidx,
    float* __restrict__ out, int P, int n_out) {
  const int lane = threadIdx.x & 63;
  const int k = blockIdx.y;
  const int wave = blockIdx.x * (blockDim.x >> 6) + (threadIdx.x >> 6);
  const int stride = gridDim.x * (blockDim.x >> 6);
  float w[32];
#pragma unroll
  for (int c = 0; c < 32; ++c) w[c] = W[((k * 32 + c) << 6) + lane];
  const int base = k * P;
  for (int p = wave; p < P; p += stride) {
    const int g = gidx[base + p];
    const int s = sidx[base + p];
    const float4* fp = (const float4*)(feats + (long)g * 32);
    float4 f[8];
#pragma unroll
    for (int j = 0; j < 8; ++j) f[j] = fp[j];
    float a0 = 0, a1 = 0, a2 = 0, a3 = 0;
#pragma unroll
    for (int j = 0; j < 8; ++j) {
      a0 = fmaf(f[j].x, w[4 * j + 0], a0);
      a1 = fmaf(f[j].y, w[4 * j + 1], a1);
      a2 = fmaf(f[j].z, w[4 * j + 2], a2);
      a3 = fmaf(f[j].w, w[4 * j + 3], a3);
    }
    if (s < n_out) atomicAdd(out + ((long)s << 6) + lane, (a0 + a1) + (a2 + a3));
  }
}

__global__ __launch_bounds__(256) void stats_kernel(
    const float4* __restrict__ out, float* __restrict__ ws, long total4) {
  const long stride = (long)gridDim.x * blockDim.x;
  float s1[4] = {0.f, 0.f, 0.f, 0.f};
  float s2[4] = {0.f, 0.f, 0.f, 0.f};
  for (long i = (long)blockIdx.x * blockDim.x + threadIdx.x; i < total4; i += stride) {
    float4 x = out[i];
    s1[0] += x.x; s2[0] += x.x * x.x;
    s1[1] += x.y; s2[1] += x.y * x.y;
    s1[2] += x.z; s2[2] += x.z * x.z;
    s1[3] += x.w; s2[3] += x.w * x.w;
  }
  __shared__ float ls[128];
  if (threadIdx.x < 128) ls[threadIdx.x] = 0.f;
  __syncthreads();
  const int cb = (threadIdx.x << 2) & 63;
#pragma unroll
  for (int j = 0; j < 4; ++j) {
    atomicAdd(&ls[cb + j], s1[j]);
    atomicAdd(&ls[64 + cb + j], s2[j]);
  }
  __syncthreads();
  if (threadIdx.x < 128) atomicAdd(&ws[threadIdx.x], ls[threadIdx.x]);
}

extern "C" void kernel_launch(void* const* d_in, const int* in_sizes, int n_in,
                              void* d_out, int out_size, void* d_ws, size_t ws_size,
                              hipStream_t stream) {
  const float* feats = (const float*)d_in[0];
  const float* W     = (const float*)d_in[1];
  const float* gamma = (const float*)d_in[2];
  const float* beta  = (const float*)d_in[3];
  const int*   gidx  = (const int*)d_in[4];
  const int*   sidx  = (const int*)d_in[5];

  const int P = in_sizes[4] / 4;    // KVOL == 4
  const int n_out = out_size / 64;  // COUT == 64
  float* out = (float*)d_out;
  float* ws  = (float*)d_ws;
  const long total4 = (long)out_size / 4;

  char* wsb = (char*)d_ws;
  const size_t count_off = 2048;
  const size_t count_bytes = ((size_t)n_out + 1) * sizeof(int);
  const size_t list_off = (count_off + count_bytes + 255) & ~(size_t)255;
  const size_t need = list_off + (size_t)n_out * sizeof(int);

  if (ws_size >= need) {
    int* nmulti = (int*)(wsb + 1024);
    int* count  = (int*)(wsb + count_off);
    int* list   = (int*)(wsb + list_off);

    hipMemsetAsync(wsb, 0, 2048, stream);            // stats + nmulti
    hipMemsetAsync(count, 0, count_bytes, stream);

    dim3 cgrid((P + 255) / 256, 4);
    count_kernel<<<cgrid, 256, 0, stream>>>(sidx, count, P);
    compact_kernel<<<(n_out + 255) / 256, 256, 0, stream>>>(count, list, nmulti, n_out);
    zero_list_kernel<<<256, 256, 0, stream>>>(list, nmulti, out);

    const int rpw = 256;  // rules per wave (4 groups of 64)
    const int waves_per_k = (P + rpw - 1) / rpw;
    dim3 vgrid((waves_per_k + 3) / 4, 4);
    conv_kernel<<<vgrid, 256, 0, stream>>>(feats, W, gidx, sidx, count, out, ws,
                                           P, n_out, rpw);
    multi_stats_kernel<<<256, 256, 0, stream>>>(list, nmulti, out, ws);
    finalize_stats_kernel<<<1, 64, 0, stream>>>(ws, gamma, beta, 1.0f / (float)n_out);
    normalize_kernel<<<2048, 256, 0, stream>>>((float4*)out, ws, total4);
  } else {
    hipMemsetAsync(d_out, 0, (size_t)out_size * sizeof(float), stream);
    hipMemsetAsync(d_ws, 0, 256 * sizeof(float), stream);
    dim3 sgrid(2048, 4);
    scatter_conv_kernel<<<sgrid, 256, 0, stream>>>(feats, W, gidx, sidx, out, P, n_out);
    stats_kernel<<<2048, 256, 0, stream>>>((const float4*)out, ws, total4);
    finalize_stats_kernel<<<1, 64, 0, stream>>>(ws, gamma, beta, 1.0f / (float)n_out);
    normalize_kernel<<<2048, 256, 0, stream>>>((float4*)out, ws, total4);
  }
}

// Round 7
// 698.676 us; speedup vs baseline: 2.1363x; 1.5162x over previous
//
#include <hip/hip_runtime.h>

#define EPS_LN 1e-4f

typedef short short8 __attribute__((ext_vector_type(8)));
typedef float f32x4 __attribute__((ext_vector_type(4)));

// f32 -> bf16 round-to-nearest-even (bit trick, 3 VALU)
__device__ __forceinline__ short f2bf(float f) {
  const unsigned u = __float_as_uint(f);
  return (short)((u + 0x7FFFu + ((u >> 16) & 1u)) >> 16);
}

// ===========================================================================
// r6 evidence: conv VALU-bound at 82% (readlane+fma = 2 VALU per useful FMA).
// r7: MFMA conv. Tile = 16 rules x 64 channels: gather feats DIRECTLY in
// A-fragment layout (lane: row=lane&15, k=8*(lane>>4)+j -> 2 dwordx4 per
// tile = 16 random 128B rows in flight per instr), convert to bf16, 4x
// mfma_f32_16x16x32_bf16 against preloaded W[k] B-fragments (16 VGPR).
// C layout (m89-verified): lane holds D[4*(lane>>4)+q][(lane&15)+16m].
// Store classification via count table: count==1 -> plain store + fused
// stats; count>=2 (~3%, pre-zeroed) -> atomicAdd, stats in scan pass.
// Aux: r5 scan-based zero/multi (r6's compact had a serialized single-
// counter atomic); count_kernel kept (known ~200us, next target).
// ws: [0,1KB) stats | [2KB) count[n_out+1]
// ===========================================================================

__global__ __launch_bounds__(256) void count_kernel(
    const int* __restrict__ sidx, int* __restrict__ count, int P) {
  const int k = blockIdx.y;
  const int p = blockIdx.x * blockDim.x + threadIdx.x;
  if (p < P) atomicAdd(&count[sidx[k * P + p]], 1);
}

__global__ __launch_bounds__(256) void zero_multi_kernel(
    const int* __restrict__ count, float* __restrict__ out, int n_out) {
  const int lane = threadIdx.x & 63;
  const int wave = (blockIdx.x * blockDim.x + threadIdx.x) >> 6;
  const int wstep = (gridDim.x * blockDim.x) >> 6;
  for (int r = wave; r < n_out; r += wstep)
    if (count[r] >= 2) out[((size_t)r << 6) + lane] = 0.f;
}

__global__ __launch_bounds__(256) void conv_mfma_kernel(
    const float* __restrict__ feats, const float* __restrict__ W,
    const int* __restrict__ gidx, const int* __restrict__ sidx,
    const int* __restrict__ count, float* __restrict__ out,
    float* __restrict__ ws, int P, int n_out, int rpw) {
  const int lane = threadIdx.x & 63;
  const int l15 = lane & 15;
  const int lh = lane >> 4;  // 0..3
  const int k = blockIdx.y;
  const int wv = blockIdx.x * (blockDim.x >> 6) + (threadIdx.x >> 6);

  __shared__ float ls[128];
  if (threadIdx.x < 128) ls[threadIdx.x] = 0.f;
  __syncthreads();

  // B fragments: wb[m][j] = W[k][ 8*lh+j ][ 16m + l15 ] as bf16
  short8 wb[4];
#pragma unroll
  for (int m = 0; m < 4; ++m) {
#pragma unroll
    for (int j = 0; j < 8; ++j) {
      const int kk = (lh << 3) + j;
      wb[m][j] = f2bf(W[(((k << 5) + kk) << 6) + (m << 4) + l15]);
    }
  }

  const long base = (long)k * P;
  const int start = wv * rpw;
  const int end = min(start + rpw, P);
  float s1[4] = {0.f, 0.f, 0.f, 0.f}, s2[4] = {0.f, 0.f, 0.f, 0.f};
  const f32x4 zero = {0.f, 0.f, 0.f, 0.f};

  if (start < end) {
    // group (64 rules) index state; sp = (s<<1) | (count>=2)
    int g = 0, sp = (n_out << 1);
    {
      const int pg = start + lane;
      if (pg < end) {
        g = gidx[base + pg];
        const int s = sidx[base + pg];
        sp = (s << 1) | (count[s] > 1 ? 1 : 0);
      }
    }

    for (int gs = start; gs < end; gs += 64) {
      // ---- issue all 4 tiles' gathers: 64 random 128B rows in flight ----
      float4 F[8];
#pragma unroll
      for (int t = 0; t < 4; ++t) {
        const int gq = __shfl(g, (t << 4) + l15);  // rule for my A-row
        const float4* fp = (const float4*)feats + ((size_t)gq << 3) + (lh << 1);
        F[2 * t] = fp[0];
        F[2 * t + 1] = fp[1];
      }
      // ---- prefetch next group's indices under this group's compute ----
      int gN = 0, spN = (n_out << 1);
      {
        const int pg = gs + 64 + lane;
        if (pg < end) {
          gN = gidx[base + pg];
          const int s = sidx[base + pg];
          spN = (s << 1) | (count[s] > 1 ? 1 : 0);
        }
      }
      // ---- per tile: cvt -> 4 MFMA -> classified store + fused stats ----
#pragma unroll
      for (int t = 0; t < 4; ++t) {
        short8 a;
#pragma unroll
        for (int j = 0; j < 4; ++j) {
          a[j] = f2bf(((const float*)&F[2 * t])[j]);
          a[4 + j] = f2bf(((const float*)&F[2 * t + 1])[j]);
        }
        const f32x4 d0 = __builtin_amdgcn_mfma_f32_16x16x32_bf16(a, wb[0], zero, 0, 0, 0);
        const f32x4 d1 = __builtin_amdgcn_mfma_f32_16x16x32_bf16(a, wb[1], zero, 0, 0, 0);
        const f32x4 d2 = __builtin_amdgcn_mfma_f32_16x16x32_bf16(a, wb[2], zero, 0, 0, 0);
        const f32x4 d3 = __builtin_amdgcn_mfma_f32_16x16x32_bf16(a, wb[3], zero, 0, 0, 0);
#pragma unroll
        for (int q = 0; q < 4; ++q) {
          const int spq = __shfl(sp, (t << 4) + (lh << 2) + q);  // rule 4lh+q
          const int srow = spq >> 1;
          const bool mu = (spq & 1) != 0;
          const bool v = srow < n_out;
          const size_t rb = ((size_t)srow << 6) + l15;
#define DO_STORE(dm, m)                                       \
          {                                                   \
            const float val = dm[q];                          \
            const float sv = (v && !mu) ? val : 0.f;          \
            s1[m] += sv;                                      \
            s2[m] = fmaf(sv, sv, s2[m]);                      \
            if (v) {                                          \
              if (mu) atomicAdd(out + rb + (m << 4), val);    \
              else out[rb + (m << 4)] = val;                  \
            }                                                 \
          }
          DO_STORE(d0, 0)
          DO_STORE(d1, 1)
          DO_STORE(d2, 2)
          DO_STORE(d3, 3)
#undef DO_STORE
        }
      }
      g = gN;
      sp = spN;
    }
  }

#pragma unroll
  for (int m = 0; m < 4; ++m) {
    atomicAdd(&ls[(m << 4) + l15], s1[m]);
    atomicAdd(&ls[64 + (m << 4) + l15], s2[m]);
  }
  __syncthreads();
  if (threadIdx.x < 128) atomicAdd(&ws[threadIdx.x], ls[threadIdx.x]);
}

// stats for multi-contribution rows (scan; runs after conv)
__global__ __launch_bounds__(256) void multi_stats_kernel(
    const int* __restrict__ count, const float* __restrict__ out,
    float* __restrict__ ws, int n_out) {
  const int lane = threadIdx.x & 63;
  const int wave = (blockIdx.x * blockDim.x + threadIdx.x) >> 6;
  const int wstep = (gridDim.x * blockDim.x) >> 6;
  float s1 = 0.f, s2 = 0.f;
  for (int r = wave; r < n_out; r += wstep) {
    if (count[r] >= 2) {
      const float v = out[((size_t)r << 6) + lane];
      s1 += v;
      s2 = fmaf(v, v, s2);
    }
  }
  __shared__ float ls[128];
  if (threadIdx.x < 128) ls[threadIdx.x] = 0.f;
  __syncthreads();
  atomicAdd(&ls[lane], s1);
  atomicAdd(&ls[64 + lane], s2);
  __syncthreads();
  if (threadIdx.x < 128) atomicAdd(&ws[threadIdx.x], ls[threadIdx.x]);
}

__global__ void finalize_stats_kernel(float* __restrict__ ws,
                                      const float* __restrict__ gamma,
                                      const float* __restrict__ beta,
                                      float inv_n) {
  const int c = threadIdx.x;  // 64 threads
  const float mean = ws[c] * inv_n;
  const float var = ws[64 + c] * inv_n - mean * mean;
  const float sc = rsqrtf(var + EPS_LN) * gamma[c];
  ws[128 + c] = sc;
  ws[192 + c] = beta[c] - mean * sc;
}

__global__ __launch_bounds__(256) void normalize_kernel(
    float4* __restrict__ out, const float* __restrict__ ws, long total4) {
  const long stride = (long)gridDim.x * blockDim.x;
  const int cb = (threadIdx.x << 2) & 63;
  const float4 sc = *(const float4*)(ws + 128 + cb);
  const float4 sh = *(const float4*)(ws + 192 + cb);
  for (long i = (long)blockIdx.x * blockDim.x + threadIdx.x; i < total4; i += stride) {
    float4 x = out[i];
    x.x = fmaxf(fmaf(x.x, sc.x, sh.x), 0.f);
    x.y = fmaxf(fmaf(x.y, sc.y, sh.y), 0.f);
    x.z = fmaxf(fmaf(x.z, sc.z, sh.z), 0.f);
    x.w = fmaxf(fmaf(x.w, sc.w, sh.w), 0.f);
    out[i] = x;
  }
}

// ---------------- fallback (if ws too small): r2 path ----------------
__global__ __launch_bounds__(256) void scatter_conv_kernel(
    const float* __restrict__ feats, const float* __restrict__ W,
    const int* __restrict__ gidx, const int* __restrict__ sidx,
    float* __restrict__ out, int P, int n_out) {
  const int lane = threadIdx.x & 63;
  const int k = blockIdx.y;
  const int wave = blockIdx.x * (blockDim.x >> 6) + (threadIdx.x >> 6);
  const int stride = gridDim.x * (blockDim.x >> 6);
  float w[32];
#pragma unroll
  for (int c = 0; c < 32; ++c) w[c] = W[((k * 32 + c) << 6) + lane];
  const int base = k * P;
  for (int p = wave; p < P; p += stride) {
    const int g = gidx[base + p];
    const int s = sidx[base + p];
    const float4* fp = (const float4*)(feats + (long)g * 32);
    float4 f[8];
#pragma unroll
    for (int j = 0; j < 8; ++j) f[j] = fp[j];
    float a0 = 0, a1 = 0, a2 = 0, a3 = 0;
#pragma unroll
    for (int j = 0; j < 8; ++j) {
      a0 = fmaf(f[j].x, w[4 * j + 0], a0);
      a1 = fmaf(f[j].y, w[4 * j + 1], a1);
      a2 = fmaf(f[j].z, w[4 * j + 2], a2);
      a3 = fmaf(f[j].w, w[4 * j + 3], a3);
    }
    if (s < n_out) atomicAdd(out + ((long)s << 6) + lane, (a0 + a1) + (a2 + a3));
  }
}

__global__ __launch_bounds__(256) void stats_kernel(
    const float4* __restrict__ out, float* __restrict__ ws, long total4) {
  const long stride = (long)gridDim.x * blockDim.x;
  float s1[4] = {0.f, 0.f, 0.f, 0.f};
  float s2[4] = {0.f, 0.f, 0.f, 0.f};
  for (long i = (long)blockIdx.x * blockDim.x + threadIdx.x; i < total4; i += stride) {
    float4 x = out[i];
    s1[0] += x.x; s2[0] += x.x * x.x;
    s1[1] += x.y; s2[1] += x.y * x.y;
    s1[2] += x.z; s2[2] += x.z * x.z;
    s1[3] += x.w; s2[3] += x.w * x.w;
  }
  __shared__ float ls[128];
  if (threadIdx.x < 128) ls[threadIdx.x] = 0.f;
  __syncthreads();
  const int cb = (threadIdx.x << 2) & 63;
#pragma unroll
  for (int j = 0; j < 4; ++j) {
    atomicAdd(&ls[cb + j], s1[j]);
    atomicAdd(&ls[64 + cb + j], s2[j]);
  }
  __syncthreads();
  if (threadIdx.x < 128) atomicAdd(&ws[threadIdx.x], ls[threadIdx.x]);
}

extern "C" void kernel_launch(void* const* d_in, const int* in_sizes, int n_in,
                              void* d_out, int out_size, void* d_ws, size_t ws_size,
                              hipStream_t stream) {
  const float* feats = (const float*)d_in[0];
  const float* W     = (const float*)d_in[1];
  const float* gamma = (const float*)d_in[2];
  const float* beta  = (const float*)d_in[3];
  const int*   gidx  = (const int*)d_in[4];
  const int*   sidx  = (const int*)d_in[5];

  const int P = in_sizes[4] / 4;    // KVOL == 4
  const int n_out = out_size / 64;  // COUT == 64
  float* out = (float*)d_out;
  float* ws  = (float*)d_ws;
  const long total4 = (long)out_size / 4;

  char* wsb = (char*)d_ws;
  const size_t count_off = 2048;
  const size_t count_bytes = ((size_t)n_out + 1) * sizeof(int);
  const size_t need = count_off + count_bytes;

  if (ws_size >= need) {
    int* count = (int*)(wsb + count_off);
    hipMemsetAsync(wsb, 0, 2048, stream);
    hipMemsetAsync(count, 0, count_bytes, stream);

    dim3 cgrid((P + 255) / 256, 4);
    count_kernel<<<cgrid, 256, 0, stream>>>(sidx, count, P);
    zero_multi_kernel<<<4096, 256, 0, stream>>>(count, out, n_out);

    const int rpw = 256;  // rules per wave (4 groups of 64 = 16 MFMA tiles)
    const int waves_per_k = (P + rpw - 1) / rpw;
    dim3 vgrid((waves_per_k + 3) / 4, 4);
    conv_mfma_kernel<<<vgrid, 256, 0, stream>>>(feats, W, gidx, sidx, count,
                                                out, ws, P, n_out, rpw);
    multi_stats_kernel<<<4096, 256, 0, stream>>>(count, out, ws, n_out);
    finalize_stats_kernel<<<1, 64, 0, stream>>>(ws, gamma, beta, 1.0f / (float)n_out);
    normalize_kernel<<<2048, 256, 0, stream>>>((float4*)out, ws, total4);
  } else {
    hipMemsetAsync(d_out, 0, (size_t)out_size * sizeof(float), stream);
    hipMemsetAsync(d_ws, 0, 256 * sizeof(float), stream);
    dim3 sgrid(2048, 4);
    scatter_conv_kernel<<<sgrid, 256, 0, stream>>>(feats, W, gidx, sidx, out, P, n_out);
    stats_kernel<<<2048, 256, 0, stream>>>((const float4*)out, ws, total4);
    finalize_stats_kernel<<<1, 64, 0, stream>>>(ws, gamma, beta, 1.0f / (float)n_out);
    normalize_kernel<<<2048, 256, 0, stream>>>((float4*)out, ws, total4);
  }
}

// Round 10
// 541.187 us; speedup vs baseline: 2.7580x; 1.2910x over previous
//
#include <hip/hip_runtime.h>

#define EPS_LN 1e-4f

typedef short short8 __attribute__((ext_vector_type(8)));
typedef float f32x4 __attribute__((ext_vector_type(4)));

// f32 -> bf16 round-to-nearest-even (bit trick, 3 VALU)
__device__ __forceinline__ short f2bf(float f) {
  const unsigned u = __float_as_uint(f);
  return (short)((u + 0x7FFFu + ((u >> 16) & 1u)) >> 16);
}

// ===========================================================================
// r7 evidence: MFMA conv works (total 1059->699); remaining ~290us is the
// aux chain: count_kernel (2.1M scattered dword atomics on a 7.8MB table),
// zero_multi scan, multi_stats scan.
// r8: (1) classification table -> 2-bit flags packed 16 rows/word (486KB,
//     L2-resident; atomicOr seen-bit, second toucher sets multi-bit);
// (2) multi-row stats TELESCOPED into conv via atomicAdd's return value:
//     sum d(s2) = sum v*(2*old+v) = (sum v)^2 for any ordering -> the
//     multi_stats kernel is gone;
// (3) zero_multi = coalesced word scan + ctz bit loop.
// conv unchanged otherwise: 16-rule x 64-ch MFMA tiles, gather direct into
// A-fragment layout (16 random 128B rows in flight per dwordx4 pair).
// ws: [0,1KB) stats | [2KB) flags[(n_out+16)/16 + 1 words]
// ===========================================================================

__global__ __launch_bounds__(256) void flag_kernel(
    const int* __restrict__ sidx, unsigned* __restrict__ flags, int P,
    int n_out) {
  const int k = blockIdx.y;
  const int p = blockIdx.x * blockDim.x + threadIdx.x;
  if (p >= P) return;
  const int s = sidx[k * P + p];
  if (s >= n_out) return;  // padding
  const unsigned sh = (s & 15) << 1;
  const unsigned old = atomicOr(&flags[s >> 4], 1u << sh);
  if (old & (1u << sh)) atomicOr(&flags[s >> 4], 2u << sh);  // multi (rare)
}

__global__ __launch_bounds__(256) void zero_multi_kernel(
    const unsigned* __restrict__ flags, float4* __restrict__ out, int nwords,
    int n_out) {
  const int stride = gridDim.x * blockDim.x;
  const float4 z = {0.f, 0.f, 0.f, 0.f};
  for (int w = blockIdx.x * blockDim.x + threadIdx.x; w < nwords; w += stride) {
    unsigned f = flags[w] & 0xAAAAAAAAu;  // multi bits
    while (f) {
      const int b = __builtin_ctz(f);
      f &= f - 1;
      const int r = (w << 4) + (b >> 1);
      if (r < n_out) {
        float4* row = out + ((size_t)r << 4);  // 64 floats
#pragma unroll
        for (int j = 0; j < 16; ++j) row[j] = z;
      }
    }
  }
}

__global__ __launch_bounds__(256) void conv_mfma_kernel(
    const float* __restrict__ feats, const float* __restrict__ W,
    const int* __restrict__ gidx, const int* __restrict__ sidx,
    const unsigned* __restrict__ flags, float* __restrict__ out,
    float* __restrict__ ws, int P, int n_out, int rpw) {
  const int lane = threadIdx.x & 63;
  const int l15 = lane & 15;
  const int lh = lane >> 4;  // 0..3
  const int k = blockIdx.y;
  const int wv = blockIdx.x * (blockDim.x >> 6) + (threadIdx.x >> 6);

  __shared__ float ls[128];
  if (threadIdx.x < 128) ls[threadIdx.x] = 0.f;
  __syncthreads();

  // B fragments: wb[m][j] = W[k][ 8*lh+j ][ 16m + l15 ] as bf16
  short8 wb[4];
#pragma unroll
  for (int m = 0; m < 4; ++m) {
#pragma unroll
    for (int j = 0; j < 8; ++j) {
      const int kk = (lh << 3) + j;
      wb[m][j] = f2bf(W[(((k << 5) + kk) << 6) + (m << 4) + l15]);
    }
  }

  const long base = (long)k * P;
  const int start = wv * rpw;
  const int end = min(start + rpw, P);
  float s1[4] = {0.f, 0.f, 0.f, 0.f}, s2[4] = {0.f, 0.f, 0.f, 0.f};
  const f32x4 zero = {0.f, 0.f, 0.f, 0.f};

  if (start < end) {
    // group (64 rules) index state; sp = (s<<1) | multi
    int g = 0, sp = (n_out << 1);
    {
      const int pg = start + lane;
      if (pg < end) {
        g = gidx[base + pg];
        const int s = sidx[base + pg];
        const unsigned mu = (flags[s >> 4] >> (((s & 15) << 1) + 1)) & 1u;
        sp = (s << 1) | (int)mu;
      }
    }

    for (int gs = start; gs < end; gs += 64) {
      // ---- issue all 4 tiles' gathers: 64 random 128B rows in flight ----
      float4 F[8];
#pragma unroll
      for (int t = 0; t < 4; ++t) {
        const int gq = __shfl(g, (t << 4) + l15);  // rule for my A-row
        const float4* fp = (const float4*)feats + ((size_t)gq << 3) + (lh << 1);
        F[2 * t] = fp[0];
        F[2 * t + 1] = fp[1];
      }
      // ---- prefetch next group's indices under this group's compute ----
      int gN = 0, spN = (n_out << 1);
      {
        const int pg = gs + 64 + lane;
        if (pg < end) {
          gN = gidx[base + pg];
          const int s = sidx[base + pg];
          const unsigned mu = (flags[s >> 4] >> (((s & 15) << 1) + 1)) & 1u;
          spN = (s << 1) | (int)mu;
        }
      }
      // ---- per tile: cvt -> 4 MFMA -> classified store + fused stats ----
#pragma unroll
      for (int t = 0; t < 4; ++t) {
        short8 a;
#pragma unroll
        for (int j = 0; j < 4; ++j) {
          a[j] = f2bf(((const float*)&F[2 * t])[j]);
          a[4 + j] = f2bf(((const float*)&F[2 * t + 1])[j]);
        }
        const f32x4 d0 = __builtin_amdgcn_mfma_f32_16x16x32_bf16(a, wb[0], zero, 0, 0, 0);
        const f32x4 d1 = __builtin_amdgcn_mfma_f32_16x16x32_bf16(a, wb[1], zero, 0, 0, 0);
        const f32x4 d2 = __builtin_amdgcn_mfma_f32_16x16x32_bf16(a, wb[2], zero, 0, 0, 0);
        const f32x4 d3 = __builtin_amdgcn_mfma_f32_16x16x32_bf16(a, wb[3], zero, 0, 0, 0);
#pragma unroll
        for (int q = 0; q < 4; ++q) {
          const int spq = __shfl(sp, (t << 4) + (lh << 2) + q);  // rule 4lh+q
          const int srow = spq >> 1;
          const bool mu = (spq & 1) != 0;
          const bool v = srow < n_out;
          const size_t rb = ((size_t)srow << 6) + l15;
#define DO_STORE(dm, m)                                                 \
          {                                                             \
            const float val = dm[q];                                    \
            if (v) {                                                    \
              s1[m] += val;                                             \
              if (mu) {                                                 \
                const float old = atomicAdd(out + rb + (m << 4), val);  \
                s2[m] = fmaf(val, 2.f * old + val, s2[m]);              \
              } else {                                                  \
                out[rb + (m << 4)] = val;                               \
                s2[m] = fmaf(val, val, s2[m]);                          \
              }                                                         \
            }                                                           \
          }
          DO_STORE(d0, 0)
          DO_STORE(d1, 1)
          DO_STORE(d2, 2)
          DO_STORE(d3, 3)
#undef DO_STORE
        }
      }
      g = gN;
      sp = spN;
    }
  }

#pragma unroll
  for (int m = 0; m < 4; ++m) {
    atomicAdd(&ls[(m << 4) + l15], s1[m]);
    atomicAdd(&ls[64 + (m << 4) + l15], s2[m]);
  }
  __syncthreads();
  if (threadIdx.x < 128) atomicAdd(&ws[threadIdx.x], ls[threadIdx.x]);
}

__global__ void finalize_stats_kernel(float* __restrict__ ws,
                                      const float* __restrict__ gamma,
                                      const float* __restrict__ beta,
                                      float inv_n) {
  const int c = threadIdx.x;  // 64 threads
  const float mean = ws[c] * inv_n;
  const float var = ws[64 + c] * inv_n - mean * mean;
  const float sc = rsqrtf(var + EPS_LN) * gamma[c];
  ws[128 + c] = sc;
  ws[192 + c] = beta[c] - mean * sc;
}

__global__ __launch_bounds__(256) void normalize_kernel(
    float4* __restrict__ out, const float* __restrict__ ws, long total4) {
  const long stride = (long)gridDim.x * blockDim.x;
  const int cb = (threadIdx.x << 2) & 63;
  const float4 sc = *(const float4*)(ws + 128 + cb);
  const float4 sh = *(const float4*)(ws + 192 + cb);
  for (long i = (long)blockIdx.x * blockDim.x + threadIdx.x; i < total4; i += stride) {
    float4 x = out[i];
    x.x = fmaxf(fmaf(x.x, sc.x, sh.x), 0.f);
    x.y = fmaxf(fmaf(x.y, sc.y, sh.y), 0.f);
    x.z = fmaxf(fmaf(x.z, sc.z, sh.z), 0.f);
    x.w = fmaxf(fmaf(x.w, sc.w, sh.w), 0.f);
    out[i] = x;
  }
}

// ---------------- fallback (if ws too small): r2 path ----------------
__global__ __launch_bounds__(256) void scatter_conv_kernel(
    const float* __restrict__ feats, const float* __restrict__ W,
    const int* __restrict__ gidx, const int* __restrict__ sidx,
    float* __restrict__ out, int P, int n_out) {
  const int lane = threadIdx.x & 63;
  const int k = blockIdx.y;
  const int wave = blockIdx.x * (blockDim.x >> 6) + (threadIdx.x >> 6);
  const int stride = gridDim.x * (blockDim.x >> 6);
  float w[32];
#pragma unroll
  for (int c = 0; c < 32; ++c) w[c] = W[((k * 32 + c) << 6) + lane];
  const int base = k * P;
  for (int p = wave; p < P; p += stride) {
    const int g = gidx[base + p];
    const int s = sidx[base + p];
    const float4* fp = (const float4*)(feats + (long)g * 32);
    float4 f[8];
#pragma unroll
    for (int j = 0; j < 8; ++j) f[j] = fp[j];
    float a0 = 0, a1 = 0, a2 = 0, a3 = 0;
#pragma unroll
    for (int j = 0; j < 8; ++j) {
      a0 = fmaf(f[j].x, w[4 * j + 0], a0);
      a1 = fmaf(f[j].y, w[4 * j + 1], a1);
      a2 = fmaf(f[j].z, w[4 * j + 2], a2);
      a3 = fmaf(f[j].w, w[4 * j + 3], a3);
    }
    if (s < n_out) atomicAdd(out + ((long)s << 6) + lane, (a0 + a1) + (a2 + a3));
  }
}

__global__ __launch_bounds__(256) void stats_kernel(
    const float4* __restrict__ out, float* __restrict__ ws, long total4) {
  const long stride = (long)gridDim.x * blockDim.x;
  float s1[4] = {0.f, 0.f, 0.f, 0.f};
  float s2[4] = {0.f, 0.f, 0.f, 0.f};
  for (long i = (long)blockIdx.x * blockDim.x + threadIdx.x; i < total4; i += stride) {
    float4 x = out[i];
    s1[0] += x.x; s2[0] += x.x * x.x;
    s1[1] += x.y; s2[1] += x.y * x.y;
    s1[2] += x.z; s2[2] += x.z * x.z;
    s1[3] += x.w; s2[3] += x.w * x.w;
  }
  __shared__ float ls[128];
  if (threadIdx.x < 128) ls[threadIdx.x] = 0.f;
  __syncthreads();
  const int cb = (threadIdx.x << 2) & 63;
#pragma unroll
  for (int j = 0; j < 4; ++j) {
    atomicAdd(&ls[cb + j], s1[j]);
    atomicAdd(&ls[64 + cb + j], s2[j]);
  }
  __syncthreads();
  if (threadIdx.x < 128) atomicAdd(&ws[threadIdx.x], ls[threadIdx.x]);
}

extern "C" void kernel_launch(void* const* d_in, const int* in_sizes, int n_in,
                              void* d_out, int out_size, void* d_ws, size_t ws_size,
                              hipStream_t stream) {
  const float* feats = (const float*)d_in[0];
  const float* W     = (const float*)d_in[1];
  const float* gamma = (const float*)d_in[2];
  const float* beta  = (const float*)d_in[3];
  const int*   gidx  = (const int*)d_in[4];
  const int*   sidx  = (const int*)d_in[5];

  const int P = in_sizes[4] / 4;    // KVOL == 4
  const int n_out = out_size / 64;  // COUT == 64
  float* out = (float*)d_out;
  float* ws  = (float*)d_ws;
  const long total4 = (long)out_size / 4;

  char* wsb = (char*)d_ws;
  const size_t flags_off = 2048;
  const int nwords = (n_out + 16) / 16 + 1;  // covers s == n_out padding word
  const size_t flags_bytes = (size_t)nwords * 4;
  const size_t need = flags_off + flags_bytes;

  if (ws_size >= need) {
    unsigned* flags = (unsigned*)(wsb + flags_off);
    hipMemsetAsync(wsb, 0, 2048, stream);           // stats block
    hipMemsetAsync(flags, 0, flags_bytes, stream);  // flag table (486 KB)

    dim3 fgrid((P + 255) / 256, 4);
    flag_kernel<<<fgrid, 256, 0, stream>>>(sidx, flags, P, n_out);
    zero_multi_kernel<<<1024, 256, 0, stream>>>(flags, (float4*)out, nwords, n_out);

    const int rpw = 256;  // rules per wave (4 groups of 64 = 16 MFMA tiles)
    const int waves_per_k = (P + rpw - 1) / rpw;
    dim3 vgrid((waves_per_k + 3) / 4, 4);
    conv_mfma_kernel<<<vgrid, 256, 0, stream>>>(feats, W, gidx, sidx, flags,
                                                out, ws, P, n_out, rpw);
    finalize_stats_kernel<<<1, 64, 0, stream>>>(ws, gamma, beta, 1.0f / (float)n_out);
    normalize_kernel<<<2048, 256, 0, stream>>>((float4*)out, ws, total4);
  } else {
    hipMemsetAsync(d_out, 0, (size_t)out_size * sizeof(float), stream);
    hipMemsetAsync(d_ws, 0, 256 * sizeof(float), stream);
    dim3 sgrid(2048, 4);
    scatter_conv_kernel<<<sgrid, 256, 0, stream>>>(feats, W, gidx, sidx, out, P, n_out);
    stats_kernel<<<2048, 256, 0, stream>>>((const float4*)out, ws, total4);
    finalize_stats_kernel<<<1, 64, 0, stream>>>(ws, gamma, beta, 1.0f / (float)n_out);
    normalize_kernel<<<2048, 256, 0, stream>>>((float4*)out, ws, total4);
  }
}